// Round 1
// baseline (1542.914 us; speedup 1.0000x reference)
//
#include <hip/hip_runtime.h>
#include <math.h>

#define BB 2
#define SS 2048
#define DD 768
#define HH 12
#define DHH 64
#define DFF 3072
#define MTOK (BB*SS)   // 4096

// ---------------------------------------------------------------------------
// Generic fp32 GEMM: C[M,N] = A[M,K] @ W[K,N] + bias, ACT=1 -> exact GELU
// 64x64 tile, BK=16, 256 threads, 4x4 micro-tile per thread.
// ---------------------------------------------------------------------------
template <int ACT>
__global__ __launch_bounds__(256) void gemm_bias(const float* __restrict__ A,
                                                 const float* __restrict__ W,
                                                 const float* __restrict__ bias,
                                                 float* __restrict__ C,
                                                 int M, int N, int K) {
    __shared__ float As[16][66];   // [k][row], pad 66 -> 2-way max on write (free)
    __shared__ float Bs[16][64];   // [k][col]

    const int tid = threadIdx.x;
    const int tx = tid & 15;        // col group
    const int ty = tid >> 4;        // row group
    const int m0 = blockIdx.x * 64;
    const int n0 = blockIdx.y * 64;

    const int a_k  = tid & 15;      // k offset for A load
    const int a_r0 = tid >> 4;      // row base (stride 16)
    const int b_c  = tid & 63;      // col for B load
    const int b_r0 = tid >> 6;      // k base (stride 4)

    float acc[4][4] = {};

    for (int k0 = 0; k0 < K; k0 += 16) {
#pragma unroll
        for (int i = 0; i < 4; ++i) {
            int r = a_r0 + i * 16;
            As[a_k][r] = A[(size_t)(m0 + r) * K + k0 + a_k];
        }
#pragma unroll
        for (int i = 0; i < 4; ++i) {
            int r = b_r0 + i * 4;
            Bs[r][b_c] = W[(size_t)(k0 + r) * N + n0 + b_c];
        }
        __syncthreads();
#pragma unroll
        for (int kk = 0; kk < 16; ++kk) {
            float a[4], b[4];
#pragma unroll
            for (int i = 0; i < 4; ++i) a[i] = As[kk][ty * 4 + i];
#pragma unroll
            for (int j = 0; j < 4; ++j) b[j] = Bs[kk][tx * 4 + j];
#pragma unroll
            for (int i = 0; i < 4; ++i)
#pragma unroll
                for (int j = 0; j < 4; ++j) acc[i][j] += a[i] * b[j];
        }
        __syncthreads();
    }

#pragma unroll
    for (int i = 0; i < 4; ++i) {
        int row = m0 + ty * 4 + i;
#pragma unroll
        for (int j = 0; j < 4; ++j) {
            int col = n0 + tx * 4 + j;
            float v = acc[i][j] + bias[col];
            if (ACT == 1) v = 0.5f * v * (1.0f + erff(v * 0.70710678118654752f));
            C[(size_t)row * N + col] = v;
        }
    }
}

// ---------------------------------------------------------------------------
// Flash-style attention, fp32. One block = 64 q-rows of one (b,h).
// Q/K/V/O in [B,S,D] layout, head h occupying columns h*64..h*64+63.
// Scale 1/sqrt(64)=0.125 folded into Q load.
// ---------------------------------------------------------------------------
__global__ __launch_bounds__(256) void attn_flash(const float* __restrict__ Q,
                                                  const float* __restrict__ K,
                                                  const float* __restrict__ V,
                                                  float* __restrict__ O) {
    __shared__ float Qs[64][65];
    __shared__ float Ks[64][65];   // reused for V
    __shared__ float Ps[64][65];

    const int tid = threadIdx.x;
    const int tx = tid & 15;
    const int ty = tid >> 4;
    const int bh = blockIdx.y;
    const int b = bh / HH, h = bh % HH;
    const int q0 = blockIdx.x * 64;
    const size_t base = ((size_t)b * SS) * DD + h * DHH;

    const int ld_d  = tid & 63;   // dim index for tile loads
    const int ld_r0 = tid >> 6;   // row base (stride 4)

#pragma unroll
    for (int i = 0; i < 16; ++i) {
        int r = i * 4 + ld_r0;
        Qs[r][ld_d] = Q[base + (size_t)(q0 + r) * DD + ld_d] * 0.125f;
    }

    float acc[4][4] = {};
    float m_run[4], l_run[4];
#pragma unroll
    for (int i = 0; i < 4; ++i) { m_run[i] = -1e30f; l_run[i] = 0.0f; }

    for (int kt = 0; kt < SS / 64; ++kt) {
        const int k0 = kt * 64;
        __syncthreads();   // previous iteration's reads of Ks(V)/Ps done
#pragma unroll
        for (int i = 0; i < 16; ++i) {
            int r = i * 4 + ld_r0;
            Ks[r][ld_d] = K[base + (size_t)(k0 + r) * DD + ld_d];
        }
        __syncthreads();

        // S tile: s[i][j] = dot(Qs[ty*4+i], Ks[tx*4+j])
        float s[4][4] = {};
#pragma unroll
        for (int d = 0; d < 64; ++d) {
            float a[4], c[4];
#pragma unroll
            for (int i = 0; i < 4; ++i) a[i] = Qs[ty * 4 + i][d];
#pragma unroll
            for (int j = 0; j < 4; ++j) c[j] = Ks[tx * 4 + j][d];
#pragma unroll
            for (int i = 0; i < 4; ++i)
#pragma unroll
                for (int j = 0; j < 4; ++j) s[i][j] += a[i] * c[j];
        }

        // online softmax per row (row group = 16 contiguous lanes)
        float p[4][4];
#pragma unroll
        for (int i = 0; i < 4; ++i) {
            float mt = fmaxf(fmaxf(s[i][0], s[i][1]), fmaxf(s[i][2], s[i][3]));
#pragma unroll
            for (int off = 1; off < 16; off <<= 1) mt = fmaxf(mt, __shfl_xor(mt, off));
            float m_new = fmaxf(m_run[i], mt);
            float corr = __expf(m_run[i] - m_new);
            float rs = 0.0f;
#pragma unroll
            for (int j = 0; j < 4; ++j) { p[i][j] = __expf(s[i][j] - m_new); rs += p[i][j]; }
#pragma unroll
            for (int off = 1; off < 16; off <<= 1) rs += __shfl_xor(rs, off);
            l_run[i] = l_run[i] * corr + rs;
            m_run[i] = m_new;
#pragma unroll
            for (int j = 0; j < 4; ++j) acc[i][j] *= corr;
        }
#pragma unroll
        for (int i = 0; i < 4; ++i)
#pragma unroll
            for (int j = 0; j < 4; ++j) Ps[ty * 4 + i][tx * 4 + j] = p[i][j];

        __syncthreads();   // Ks reads + Ps writes done
#pragma unroll
        for (int i = 0; i < 16; ++i) {
            int r = i * 4 + ld_r0;
            Ks[r][ld_d] = V[base + (size_t)(k0 + r) * DD + ld_d];  // V tile
        }
        __syncthreads();

        // acc += P @ V
#pragma unroll
        for (int c = 0; c < 64; ++c) {
            float pr[4], vv[4];
#pragma unroll
            for (int i = 0; i < 4; ++i) pr[i] = Ps[ty * 4 + i][c];
#pragma unroll
            for (int j = 0; j < 4; ++j) vv[j] = Ks[c][tx * 4 + j];
#pragma unroll
            for (int i = 0; i < 4; ++i)
#pragma unroll
                for (int j = 0; j < 4; ++j) acc[i][j] += pr[i] * vv[j];
        }
    }

#pragma unroll
    for (int i = 0; i < 4; ++i) {
        float inv = 1.0f / l_run[i];
        int row = q0 + ty * 4 + i;
#pragma unroll
        for (int j = 0; j < 4; ++j) {
            int col = tx * 4 + j;
            O[base + (size_t)row * DD + col] = acc[i][j] * inv;
        }
    }
}

// ---------------------------------------------------------------------------
// out = LayerNorm(a + b) * g + be   (row = 768 elements, one block per row)
// ---------------------------------------------------------------------------
__global__ __launch_bounds__(256) void add_ln(const float* __restrict__ a,
                                              const float* __restrict__ bsrc,
                                              const float* __restrict__ g,
                                              const float* __restrict__ be,
                                              float* __restrict__ out) {
    const int row = blockIdx.x;
    const int tid = threadIdx.x;
    float x[3];
    float s = 0.0f, s2 = 0.0f;
#pragma unroll
    for (int i = 0; i < 3; ++i) {
        int c = tid + i * 256;
        float v = a[(size_t)row * DD + c] + bsrc[(size_t)row * DD + c];
        x[i] = v; s += v; s2 += v * v;
    }
#pragma unroll
    for (int off = 32; off; off >>= 1) {
        s  += __shfl_down(s, off);
        s2 += __shfl_down(s2, off);
    }
    __shared__ float ws[8];
    const int wid = tid >> 6, lane = tid & 63;
    if (lane == 0) { ws[wid] = s; ws[4 + wid] = s2; }
    __syncthreads();
    if (tid == 0) {
        ws[0] = ws[0] + ws[1] + ws[2] + ws[3];
        ws[4] = ws[4] + ws[5] + ws[6] + ws[7];
    }
    __syncthreads();
    const float mean = ws[0] * (1.0f / DD);
    const float var  = ws[4] * (1.0f / DD) - mean * mean;
    const float inv  = rsqrtf(var + 1e-5f);
#pragma unroll
    for (int i = 0; i < 3; ++i) {
        int c = tid + i * 256;
        out[(size_t)row * DD + c] = (x[i] - mean) * inv * g[c] + be[c];
    }
}

// ---------------------------------------------------------------------------
extern "C" void kernel_launch(void* const* d_in, const int* in_sizes, int n_in,
                              void* d_out, int out_size, void* d_ws, size_t ws_size,
                              hipStream_t stream) {
    const float* x  = (const float*)d_in[0];
    const float* Wq = (const float*)d_in[1];
    const float* bq = (const float*)d_in[2];
    const float* Wk = (const float*)d_in[3];
    const float* bk = (const float*)d_in[4];
    const float* Wv = (const float*)d_in[5];
    const float* bv = (const float*)d_in[6];
    const float* Wo = (const float*)d_in[7];
    const float* bo = (const float*)d_in[8];
    const float* W1 = (const float*)d_in[9];
    const float* b1 = (const float*)d_in[10];
    const float* W2 = (const float*)d_in[11];
    const float* b2 = (const float*)d_in[12];
    const float* g1 = (const float*)d_in[13];
    const float* be1= (const float*)d_in[14];
    const float* g2 = (const float*)d_in[15];
    const float* be2= (const float*)d_in[16];
    float* out = (float*)d_out;

    float* ws = (float*)d_ws;
    const size_t TOK = (size_t)MTOK * DD;           // 3,145,728 floats
    float* Qb   = ws;                                // [4096,768]
    float* Kb   = ws + TOK;                          // [4096,768]
    float* Vb   = ws + 2 * TOK;                      // [4096,768]
    float* Ctx  = ws + 3 * TOK;                      // [4096,768]
    float* Hff  = ws + 4 * TOK;                      // [4096,3072]
    float* Proj = Qb;   // reuse after attention
    float* X2   = Kb;   // reuse after proj
    float* F2   = Vb;   // reuse after ffn1

    dim3 blk(256);
    dim3 gProj(MTOK / 64, DD / 64);     // 64 x 12
    dim3 gFfn1(MTOK / 64, DFF / 64);    // 64 x 48
    dim3 gAttn(SS / 64, BB * HH);       // 32 x 24

    // QKV projections
    gemm_bias<0><<<gProj, blk, 0, stream>>>(x, Wq, bq, Qb, MTOK, DD, DD);
    gemm_bias<0><<<gProj, blk, 0, stream>>>(x, Wk, bk, Kb, MTOK, DD, DD);
    gemm_bias<0><<<gProj, blk, 0, stream>>>(x, Wv, bv, Vb, MTOK, DD, DD);
    // attention
    attn_flash<<<gAttn, blk, 0, stream>>>(Qb, Kb, Vb, Ctx);
    // output projection
    gemm_bias<0><<<gProj, blk, 0, stream>>>(Ctx, Wo, bo, Proj, MTOK, DD, DD);
    // residual + LN1
    add_ln<<<dim3(MTOK), blk, 0, stream>>>(x, Proj, g1, be1, X2);
    // FFN
    gemm_bias<1><<<gFfn1, blk, 0, stream>>>(X2, W1, b1, Hff, MTOK, DFF, DD);
    gemm_bias<0><<<gProj, blk, 0, stream>>>(Hff, W2, b2, F2, MTOK, DD, DFF);
    // residual + LN2
    add_ln<<<dim3(MTOK), blk, 0, stream>>>(X2, F2, g2, be2, out);
}

// Round 3
// 381.947 us; speedup vs baseline: 4.0396x; 4.0396x over previous
//
#include <hip/hip_runtime.h>
#include <math.h>

#define BB 2
#define SS 2048
#define DD 768
#define HH 12
#define DHH 64
#define DFFN 3072
#define MTOK (BB*SS)   // 4096

typedef __attribute__((ext_vector_type(8))) __bf16 bf16x8;
typedef __attribute__((ext_vector_type(4))) float f32x4;

__device__ __forceinline__ unsigned short f2bf(float f) {
    unsigned int b = __builtin_bit_cast(unsigned int, f);
    b += 0x7FFFu + ((b >> 16) & 1u);           // RNE
    return (unsigned short)(b >> 16);
}

__device__ __forceinline__ void gload_lds16(const void* g, void* l) {
    __builtin_amdgcn_global_load_lds((const __attribute__((address_space(1))) unsigned int*)g,
                                     (__attribute__((address_space(3))) unsigned int*)l,
                                     16, 0, 0);
}

// ---------------------------------------------------------------------------
// bf16 MFMA GEMM: C[M,N] = A[M,K](bf16) @ Bt[N,K](bf16)^T + bias
// 128x128 tile, BK=64, 4 waves, each wave 64x64 (4x4 frags of 16x16x32).
// LDS XOR-swizzled (chunk ^ (row&7)) via pre-swizzled global_load_lds source.
// ACT=1 -> exact GELU. OBF=1 -> bf16 output, else fp32.
// ---------------------------------------------------------------------------
template <int ACT, int OBF>
__global__ __launch_bounds__(256) void gemm_mfma(const unsigned short* __restrict__ A,
                                                 const unsigned short* __restrict__ Bt,
                                                 const float* __restrict__ bias,
                                                 void* __restrict__ Cout,
                                                 int M, int N, int K) {
    __shared__ unsigned short As[128 * 64];
    __shared__ unsigned short Bs[128 * 64];
    const int tid = threadIdx.x;
    const int lane = tid & 63;
    const int w = tid >> 6;
    const int l15 = lane & 15, l4 = lane >> 4;
    const int m0 = blockIdx.x * 128;
    const int n0 = blockIdx.y * 128;
    const int wr = (w >> 1) * 64;
    const int wc = (w & 1) * 64;

    f32x4 acc[4][4] = {};

    // staging slots: 1024 chunks of 16B per tile; wave w: slots w*256 + i*64 + lane
    int srow[4], scd[4];
#pragma unroll
    for (int i = 0; i < 4; ++i) {
        int s = w * 256 + i * 64 + lane;
        srow[i] = s >> 3;                          // row (0..127), 8 chunks/row
        scd[i] = (((s & 7) ^ (srow[i] & 7))) * 8;  // swizzled source chunk (elem offset)
    }

    for (int k0 = 0; k0 < K; k0 += 64) {
        __syncthreads();
#pragma unroll
        for (int i = 0; i < 4; ++i) {
            const unsigned short* gA = A + (size_t)(m0 + srow[i]) * K + k0 + scd[i];
            gload_lds16(gA, &As[(w * 256 + i * 64) * 8]);
        }
#pragma unroll
        for (int i = 0; i < 4; ++i) {
            const unsigned short* gB = Bt + (size_t)(n0 + srow[i]) * K + k0 + scd[i];
            gload_lds16(gB, &Bs[(w * 256 + i * 64) * 8]);
        }
        __syncthreads();
#pragma unroll
        for (int ks = 0; ks < 2; ++ks) {
            bf16x8 af[4], bfr[4];
#pragma unroll
            for (int m = 0; m < 4; ++m) {
                int r = wr + m * 16 + l15;
                int c = (ks * 4 + l4) ^ (r & 7);
                af[m] = *(const bf16x8*)&As[(r * 8 + c) * 8];
            }
#pragma unroll
            for (int n = 0; n < 4; ++n) {
                int r = wc + n * 16 + l15;
                int c = (ks * 4 + l4) ^ (r & 7);
                bfr[n] = *(const bf16x8*)&Bs[(r * 8 + c) * 8];
            }
#pragma unroll
            for (int m = 0; m < 4; ++m)
#pragma unroll
                for (int n = 0; n < 4; ++n)
                    acc[m][n] = __builtin_amdgcn_mfma_f32_16x16x32_bf16(af[m], bfr[n], acc[m][n], 0, 0, 0);
        }
    }

#pragma unroll
    for (int n = 0; n < 4; ++n) {
        int col = n0 + wc + n * 16 + l15;
        float bv = bias[col];
#pragma unroll
        for (int m = 0; m < 4; ++m) {
#pragma unroll
            for (int r = 0; r < 4; ++r) {
                int row = m0 + wr + m * 16 + l4 * 4 + r;
                float v = acc[m][n][r] + bv;
                if (ACT) v = 0.5f * v * (1.0f + erff(v * 0.70710678118654752f));
                if (OBF) ((unsigned short*)Cout)[(size_t)row * N + col] = f2bf(v);
                else     ((float*)Cout)[(size_t)row * N + col] = v;
            }
        }
    }
}

// ---------------------------------------------------------------------------
// MFMA flash attention. Block = 64 q-rows of one (b,h); 4 waves x 16 q-rows.
// QKV: [4096][2304] bf16 (Q|K|V col-blocks). Vt: [24][64][2048] bf16.
// Ctx out: [4096][768] bf16. Scale 0.125 applied on S in f32.
// ---------------------------------------------------------------------------
__global__ __launch_bounds__(256) void attn_mfma(const unsigned short* __restrict__ QKV,
                                                 const unsigned short* __restrict__ Vt,
                                                 unsigned short* __restrict__ Ctx) {
    __shared__ unsigned short Ks[64 * 64];
    __shared__ unsigned short Vs[64 * 64];
    __shared__ unsigned short Ps[4 * 1024];
    const int tid = threadIdx.x;
    const int lane = tid & 63;
    const int w = tid >> 6;
    const int l15 = lane & 15, l4 = lane >> 4;
    const int bh = blockIdx.y;
    const int b = bh / HH, h = bh % HH;
    const int q0 = blockIdx.x * 64;
    unsigned short* pw = Ps + w * 1024;

    // Q fragments in registers (wave's 16 q-rows x 64 dh)
    bf16x8 qf[2];
    {
        int qr = b * SS + q0 + w * 16 + l15;
        const unsigned short* qp = QKV + (size_t)qr * 2304 + h * 64 + l4 * 8;
        qf[0] = *(const bf16x8*)qp;
        qf[1] = *(const bf16x8*)(qp + 32);
    }

    f32x4 oacc[4] = {};
    float m_run[4], l_run[4];
#pragma unroll
    for (int r = 0; r < 4; ++r) { m_run[r] = -1e30f; l_run[r] = 0.0f; }

    // staging slots: 512 chunks per 8KB tile; wave w: slots w*128 + i*64 + lane
    int arow[2], acd[2];
#pragma unroll
    for (int i = 0; i < 2; ++i) {
        int s = w * 128 + i * 64 + lane;
        arow[i] = s >> 3;
        acd[i] = ((s & 7) ^ (arow[i] & 7)) * 8;
    }

    for (int kt = 0; kt < SS / 64; ++kt) {
        const int k0 = kt * 64;
        __syncthreads();
#pragma unroll
        for (int i = 0; i < 2; ++i) {
            const unsigned short* gK = QKV + (size_t)(b * SS + k0 + arow[i]) * 2304 + DD + h * 64 + acd[i];
            gload_lds16(gK, &Ks[(w * 128 + i * 64) * 8]);
        }
#pragma unroll
        for (int i = 0; i < 2; ++i) {
            const unsigned short* gV = Vt + (size_t)(bh * 64 + arow[i]) * SS + k0 + acd[i];
            gload_lds16(gV, &Vs[(w * 128 + i * 64) * 8]);
        }
        __syncthreads();

        // S = Q K^T   (s4[n]: q rows (l4*4+r), kv cols n*16+l15)
        f32x4 s4[4] = {};
#pragma unroll
        for (int ks = 0; ks < 2; ++ks) {
#pragma unroll
            for (int n = 0; n < 4; ++n) {
                int r = n * 16 + l15;
                int c = (ks * 4 + l4) ^ (r & 7);
                bf16x8 kf = *(const bf16x8*)&Ks[(r * 8 + c) * 8];
                s4[n] = __builtin_amdgcn_mfma_f32_16x16x32_bf16(qf[ks], kf, s4[n], 0, 0, 0);
            }
        }

        // online softmax (scale 0.125 in f32)
        float p[4][4];
        float corr[4];
#pragma unroll
        for (int r = 0; r < 4; ++r) {
            float mt = fmaxf(fmaxf(s4[0][r], s4[1][r]), fmaxf(s4[2][r], s4[3][r])) * 0.125f;
#pragma unroll
            for (int off = 1; off < 16; off <<= 1) mt = fmaxf(mt, __shfl_xor(mt, off));
            float mn = fmaxf(m_run[r], mt);
            corr[r] = __expf(m_run[r] - mn);
            float rs = 0.0f;
#pragma unroll
            for (int n = 0; n < 4; ++n) {
                float pv = __expf(s4[n][r] * 0.125f - mn);
                p[n][r] = pv; rs += pv;
            }
#pragma unroll
            for (int off = 1; off < 16; off <<= 1) rs += __shfl_xor(rs, off);
            l_run[r] = l_run[r] * corr[r] + rs;
            m_run[r] = mn;
        }
#pragma unroll
        for (int n = 0; n < 4; ++n)
#pragma unroll
            for (int r = 0; r < 4; ++r) oacc[n][r] *= corr[r];

        // P -> LDS (bf16, XOR-swizzled rows of 128B)
#pragma unroll
        for (int n = 0; n < 4; ++n) {
            int col = n * 16 + l15;
#pragma unroll
            for (int r = 0; r < 4; ++r) {
                int q = l4 * 4 + r;
                int byte = q * 128 + (((col >> 3) ^ (q & 7)) * 16) + (col & 7) * 2;
                *(unsigned short*)((char*)pw + byte) = f2bf(p[n][r]);
            }
        }

        // O += P @ V
#pragma unroll
        for (int ks = 0; ks < 2; ++ks) {
            int cpa = (ks * 4 + l4) ^ (l15 & 7);
            bf16x8 pa = *(const bf16x8*)((const char*)pw + l15 * 128 + cpa * 16);
#pragma unroll
            for (int n = 0; n < 4; ++n) {
                int r = n * 16 + l15;
                int c = (ks * 4 + l4) ^ (r & 7);
                bf16x8 vf = *(const bf16x8*)&Vs[(r * 8 + c) * 8];
                oacc[n] = __builtin_amdgcn_mfma_f32_16x16x32_bf16(pa, vf, oacc[n], 0, 0, 0);
            }
        }
    }

    // epilogue: O / l, write bf16 Ctx
#pragma unroll
    for (int n = 0; n < 4; ++n) {
        int col = h * 64 + n * 16 + l15;
#pragma unroll
        for (int r = 0; r < 4; ++r) {
            int q = b * SS + q0 + w * 16 + l4 * 4 + r;
            Ctx[(size_t)q * DD + col] = f2bf(oacc[n][r] / l_run[r]);
        }
    }
}

// ---------------------------------------------------------------------------
// V transpose: QKV V-block [s][dh] -> Vt [bh][dh][s]  (bf16)
// ---------------------------------------------------------------------------
__global__ __launch_bounds__(256) void v_transpose(const unsigned short* __restrict__ QKV,
                                                   unsigned short* __restrict__ Vt) {
    __shared__ unsigned short t[64][66];
    const int tid = threadIdx.x;
    const int bh = blockIdx.y, b = bh / HH, h = bh % HH;
    const int s0 = blockIdx.x * 64;
    const int c = tid & 63, r0 = tid >> 6;
#pragma unroll
    for (int i = 0; i < 16; ++i) {
        int r = i * 4 + r0;
        t[r][c] = QKV[(size_t)(b * SS + s0 + r) * 2304 + 1536 + h * 64 + c];
    }
    __syncthreads();
#pragma unroll
    for (int i = 0; i < 16; ++i) {
        int r = i * 4 + r0;   // dh
        Vt[((size_t)bh * 64 + r) * SS + s0 + c] = t[c][r];
    }
}

// ---------------------------------------------------------------------------
// Weight transpose+convert: W fp32 [K][N] -> Wt bf16 [rowoff+N][K]
// ---------------------------------------------------------------------------
__global__ __launch_bounds__(256) void wtrans(const float* __restrict__ W,
                                              unsigned short* __restrict__ Wt,
                                              int K, int N, int rowoff) {
    __shared__ float t[32][33];
    const int tid = threadIdx.x;
    const int k0 = blockIdx.x * 32, n0 = blockIdx.y * 32;
    const int c = tid & 31, r0 = tid >> 5;
#pragma unroll
    for (int i = 0; i < 4; ++i) {
        int r = i * 8 + r0;
        t[r][c] = W[(size_t)(k0 + r) * N + n0 + c];
    }
    __syncthreads();
#pragma unroll
    for (int i = 0; i < 4; ++i) {
        int r = i * 8 + r0;
        Wt[(size_t)(rowoff + n0 + r) * K + k0 + c] = f2bf(t[c][r]);
    }
}

__global__ __launch_bounds__(256) void f2b_vec(const float* __restrict__ in,
                                               unsigned short* __restrict__ out, int n4) {
    int i = blockIdx.x * 256 + threadIdx.x;
    if (i < n4) {
        float4 v = ((const float4*)in)[i];
        unsigned long long pk = (unsigned long long)f2bf(v.x)
                              | ((unsigned long long)f2bf(v.y) << 16)
                              | ((unsigned long long)f2bf(v.z) << 32)
                              | ((unsigned long long)f2bf(v.w) << 48);
        ((unsigned long long*)out)[i] = pk;
    }
}

__global__ __launch_bounds__(256) void bias_concat(const float* __restrict__ q,
                                                   const float* __restrict__ k,
                                                   const float* __restrict__ v,
                                                   float* __restrict__ o) {
    int i = blockIdx.x * 256 + threadIdx.x;
    if (i < DD) { o[i] = q[i]; o[DD + i] = k[i]; o[2 * DD + i] = v[i]; }
}

// ---------------------------------------------------------------------------
// out_f = LayerNorm(a+b)*g+be ; WB=1 also writes bf16 copy
// ---------------------------------------------------------------------------
template <int WB>
__global__ __launch_bounds__(256) void add_ln(const float* __restrict__ a,
                                              const float* __restrict__ bsrc,
                                              const float* __restrict__ g,
                                              const float* __restrict__ be,
                                              float* __restrict__ outf,
                                              unsigned short* __restrict__ outb) {
    const int row = blockIdx.x;
    const int tid = threadIdx.x;
    float x[3];
    float s = 0.0f, s2 = 0.0f;
#pragma unroll
    for (int i = 0; i < 3; ++i) {
        int c = tid + i * 256;
        float v = a[(size_t)row * DD + c] + bsrc[(size_t)row * DD + c];
        x[i] = v; s += v; s2 += v * v;
    }
#pragma unroll
    for (int off = 32; off; off >>= 1) {
        s += __shfl_down(s, off);
        s2 += __shfl_down(s2, off);
    }
    __shared__ float ws[8];
    const int wid = tid >> 6, lane = tid & 63;
    if (lane == 0) { ws[wid] = s; ws[4 + wid] = s2; }
    __syncthreads();
    if (tid == 0) {
        ws[0] = ws[0] + ws[1] + ws[2] + ws[3];
        ws[4] = ws[4] + ws[5] + ws[6] + ws[7];
    }
    __syncthreads();
    const float mean = ws[0] * (1.0f / DD);
    const float var = ws[4] * (1.0f / DD) - mean * mean;
    const float inv = rsqrtf(var + 1e-5f);
#pragma unroll
    for (int i = 0; i < 3; ++i) {
        int c = tid + i * 256;
        float res = (x[i] - mean) * inv * g[c] + be[c];
        outf[(size_t)row * DD + c] = res;
        if (WB) outb[(size_t)row * DD + c] = f2bf(res);
    }
}

// ---------------------------------------------------------------------------
extern "C" void kernel_launch(void* const* d_in, const int* in_sizes, int n_in,
                              void* d_out, int out_size, void* d_ws, size_t ws_size,
                              hipStream_t stream) {
    const float* x   = (const float*)d_in[0];
    const float* Wq  = (const float*)d_in[1];
    const float* bq  = (const float*)d_in[2];
    const float* Wk  = (const float*)d_in[3];
    const float* bk  = (const float*)d_in[4];
    const float* Wv  = (const float*)d_in[5];
    const float* bv  = (const float*)d_in[6];
    const float* Wo  = (const float*)d_in[7];
    const float* bo  = (const float*)d_in[8];
    const float* W1  = (const float*)d_in[9];
    const float* b1  = (const float*)d_in[10];
    const float* W2  = (const float*)d_in[11];
    const float* b2  = (const float*)d_in[12];
    const float* g1  = (const float*)d_in[13];
    const float* be1 = (const float*)d_in[14];
    const float* g2  = (const float*)d_in[15];
    const float* be2 = (const float*)d_in[16];
    float* out = (float*)d_out;

    char* w8 = (char*)d_ws;
    // region 0: QKV [0,18874368) + Vt [18874368,25165824) ; Hff overlays [0,25165824)
    unsigned short* QKV = (unsigned short*)w8;
    unsigned short* Vt  = (unsigned short*)(w8 + 18874368);
    unsigned short* Hff = (unsigned short*)w8;
    char* p = w8 + 25165824;
    unsigned short* Ctxb  = (unsigned short*)p; p += 6291456;
    unsigned short* xb    = (unsigned short*)p; p += 6291456;   // also X2b
    unsigned short* Wqkvt = (unsigned short*)p; p += 3538944;
    unsigned short* Wot   = (unsigned short*)p; p += 1179648;
    unsigned short* W1t   = (unsigned short*)p; p += 4718592;
    unsigned short* W2t   = (unsigned short*)p; p += 4718592;
    float* bqkv = (float*)p; p += 9216 + 256;
    float* Proj = (float*)p; p += 12582912;                     // also F2
    float* X2   = (float*)p; p += 12582912;

    dim3 blk(256);

    // prep: conversions / transposes
    f2b_vec<<<dim3(3072), blk, 0, stream>>>(x, xb, MTOK * DD / 4);
    wtrans<<<dim3(24, 24), blk, 0, stream>>>(Wq, Wqkvt, DD, DD, 0);
    wtrans<<<dim3(24, 24), blk, 0, stream>>>(Wk, Wqkvt, DD, DD, DD);
    wtrans<<<dim3(24, 24), blk, 0, stream>>>(Wv, Wqkvt, DD, DD, 2 * DD);
    wtrans<<<dim3(24, 24), blk, 0, stream>>>(Wo, Wot, DD, DD, 0);
    wtrans<<<dim3(24, 96), blk, 0, stream>>>(W1, W1t, DD, DFFN, 0);
    wtrans<<<dim3(96, 24), blk, 0, stream>>>(W2, W2t, DFFN, DD, 0);
    bias_concat<<<dim3(3), blk, 0, stream>>>(bq, bk, bv, bqkv);

    // fused QKV projection -> QKV bf16 [4096][2304]
    gemm_mfma<0, 1><<<dim3(32, 18), blk, 0, stream>>>(xb, Wqkvt, bqkv, QKV, MTOK, 3 * DD, DD);
    // V transpose -> Vt [24][64][2048]
    v_transpose<<<dim3(32, 24), blk, 0, stream>>>(QKV, Vt);
    // attention -> Ctxb bf16
    attn_mfma<<<dim3(32, 24), blk, 0, stream>>>(QKV, Vt, Ctxb);
    // output projection (fp32 out for residual)
    gemm_mfma<0, 0><<<dim3(32, 6), blk, 0, stream>>>(Ctxb, Wot, bo, Proj, MTOK, DD, DD);
    // residual + LN1 -> X2 fp32 + X2b bf16 (in xb region)
    add_ln<1><<<dim3(MTOK), blk, 0, stream>>>(x, Proj, g1, be1, X2, xb);
    // FFN1 + GELU -> Hff bf16
    gemm_mfma<1, 1><<<dim3(32, 24), blk, 0, stream>>>(xb, W1t, b1, Hff, MTOK, DFFN, DD);
    // FFN2 -> F2 fp32 (Proj region)
    gemm_mfma<0, 0><<<dim3(32, 6), blk, 0, stream>>>(Hff, W2t, b2, Proj, MTOK, DD, DFFN);
    // residual + LN2 -> out
    add_ln<0><<<dim3(MTOK), blk, 0, stream>>>(X2, Proj, g2, be2, out, nullptr);
}